// Round 1
// baseline (706.498 us; speedup 1.0000x reference)
//
#include <hip/hip_runtime.h>
#include <hip/hip_bf16.h>

#define GRIDW 480
#define CELLS_PER_B (GRIDW*GRIDW)       // 230400
#define NCELL (4*CELLS_PER_B)           // 921600
#define NPTS  400000
#define NPB   100000
#define H1D 128
#define H2D 256
#define DD 64
#define SCAN_BLK 900                    // NCELL / 1024

// order-preserving float->uint key (max over keys == max over floats)
static __device__ __forceinline__ unsigned fkey(float f){
  unsigned u = __float_as_uint(f);
  return (u & 0x80000000u) ? ~u : (u | 0x80000000u);
}
static __device__ __forceinline__ float fdec(unsigned k){
  unsigned u = (k & 0x80000000u) ? (k ^ 0x80000000u) : ~k;
  return __uint_as_float(u);
}

__global__ void k_clear(unsigned* __restrict__ flags){
  int i = blockIdx.x*256 + threadIdx.x;
  if (i < NCELL) flags[i] = 0u;
}

__global__ void k_scatter_flags(const int* __restrict__ xy, unsigned* __restrict__ flags){
  int p = blockIdx.x*256 + threadIdx.x;
  if (p >= NPTS) return;
  int b = p / NPB;
  int x = xy[2*p], y = xy[2*p+1];
  flags[(b*GRIDW + x)*GRIDW + y] = 1u;
}

// 1024 cells per block: per-thread 4 cells, block exclusive scan
__global__ void k_scan(const unsigned* __restrict__ flags, unsigned* __restrict__ rank,
                       unsigned* __restrict__ bsum){
  __shared__ unsigned sh[256];
  int tid = threadIdx.x;
  int base = blockIdx.x*1024 + tid*4;
  unsigned v0=flags[base], v1=flags[base+1], v2=flags[base+2], v3=flags[base+3];
  unsigned s = v0+v1+v2+v3;
  sh[tid]=s; __syncthreads();
  for (int off=1; off<256; off<<=1){
    unsigned t = (tid>=off) ? sh[tid-off] : 0u;
    __syncthreads();
    sh[tid] += t;
    __syncthreads();
  }
  unsigned excl = sh[tid]-s;
  if (tid==255) bsum[blockIdx.x] = sh[255];
  rank[base]   = excl;
  rank[base+1] = excl+v0;
  rank[base+2] = excl+v0+v1;
  rank[base+3] = excl+v0+v1+v2;
}

__global__ void k_scan_bsum(unsigned* __restrict__ bsum){
  __shared__ unsigned sh[1024];
  int tid = threadIdx.x;
  unsigned v = (tid<SCAN_BLK) ? bsum[tid] : 0u;
  sh[tid]=v; __syncthreads();
  for (int off=1; off<1024; off<<=1){
    unsigned t = (tid>=off) ? sh[tid-off] : 0u;
    __syncthreads();
    sh[tid] += t;
    __syncthreads();
  }
  if (tid<SCAN_BLK) bsum[tid] = sh[tid]-v;
}

__global__ void k_emit_unq(const unsigned* __restrict__ flags, unsigned* __restrict__ rank,
                           const unsigned* __restrict__ bsum, float* __restrict__ out){
  int i = blockIdx.x*256 + threadIdx.x;
  if (i >= NCELL) return;
  unsigned r = rank[i] + bsum[i>>10];
  rank[i] = r;                       // finalize global rank for the MLP pass
  if (flags[i]){
    int b = i / CELLS_PER_B;
    int rem = i - b*CELLS_PER_B;
    int x = rem / GRIDW;
    int y = rem - x*GRIDW;
    float* o = out + 3u*r;           // unq written as floats (harness reads f32)
    o[0]=(float)b; o[1]=(float)x; o[2]=(float)y;
  }
}

__global__ void k_init_pooled(unsigned* __restrict__ pooled, int n){
  for (int i = blockIdx.x*256+threadIdx.x; i < n; i += gridDim.x*256)
    pooled[i] = 0u;                  // fkey domain minimum
}

__global__ void k_decode(unsigned* __restrict__ pooled, int n){
  for (int i = blockIdx.x*256+threadIdx.x; i < n; i += gridDim.x*256)
    ((float*)pooled)[i] = fdec(pooled[i]);
}

// fused MLP (3->128->256->64) + atomic segment-max scatter.
// 256 threads, 64-point tile; h1 (64x128) and one 64-col h2 chunk in LDS.
__global__ __launch_bounds__(256,2) void k_mlp_scatter(
    const float* __restrict__ pt, const int* __restrict__ xy,
    const float* __restrict__ W1, const float* __restrict__ b1,
    const float* __restrict__ W2, const float* __restrict__ b2,
    const float* __restrict__ W3, const float* __restrict__ b3,
    const unsigned* __restrict__ rank, unsigned* __restrict__ pooled)
{
  __shared__ float    in_s[64][4];
  __shared__ unsigned r_s[64];
  __shared__ float    h1s[64][H1D+4];  // pad 4 floats: breaks bank aliasing, keeps 16B align
  __shared__ float    h2s[64][68];
  int tid = threadIdx.x;
  int p0g = blockIdx.x*64;
  if (tid < 64){
    int pg = p0g + tid;
    int b = pg / NPB;
    int x = xy[2*pg], y = xy[2*pg+1];
    r_s[tid] = rank[(b*GRIDW+x)*GRIDW + y];
    in_s[tid][0]=pt[pg*3+0]; in_s[tid][1]=pt[pg*3+1]; in_s[tid][2]=pt[pg*3+2];
  }
  __syncthreads();

  // layer 1: 64x128 elems, 3-wide dot
  #pragma unroll
  for (int it=0; it<32; ++it){
    int e = it*256 + tid;
    int p = e >> 7, j = e & 127;
    float v = b1[j]
      + in_s[p][0]*W1[j]
      + in_s[p][1]*W1[H1D + j]
      + in_s[p][2]*W1[2*H1D + j];
    h1s[p][j] = fmaxf(v, 0.f);
  }
  __syncthreads();

  const int ty = tid >> 4, tx = tid & 15;
  const int prow = ty*4, d0 = tx*4;     // 16x16 thread grid of 4x4 register tiles
  float facc[4][4];
  #pragma unroll
  for(int i=0;i<4;i++){
    #pragma unroll
    for(int j=0;j<4;j++) facc[i][j]=0.f;
  }

  for (int jc=0; jc<H2D; jc+=64){
    // ---- layer 2 chunk: h2[64][jc..jc+64) ----
    float acc[4][4];
    #pragma unroll
    for(int i=0;i<4;i++){
      #pragma unroll
      for(int j=0;j<4;j++) acc[i][j]=0.f;
    }
    for (int k4=0; k4<H1D; k4+=4){
      float4 aa[4], ww[4];
      #pragma unroll
      for(int i=0;i<4;i++) aa[i] = *(const float4*)&h1s[prow+i][k4];
      #pragma unroll
      for(int kk=0;kk<4;kk++) ww[kk] = *(const float4*)&W2[(k4+kk)*H2D + jc + d0];
      #pragma unroll
      for(int kk=0;kk<4;kk++){
        #pragma unroll
        for(int i=0;i<4;i++){
          float av = ((const float*)&aa[i])[kk];
          acc[i][0]=fmaf(av, ww[kk].x, acc[i][0]);
          acc[i][1]=fmaf(av, ww[kk].y, acc[i][1]);
          acc[i][2]=fmaf(av, ww[kk].z, acc[i][2]);
          acc[i][3]=fmaf(av, ww[kk].w, acc[i][3]);
        }
      }
    }
    __syncthreads();   // previous chunk's layer-3 reads of h2s are done
    #pragma unroll
    for(int i=0;i<4;i++){
      #pragma unroll
      for(int j=0;j<4;j++)
        h2s[prow+i][d0+j] = fmaxf(acc[i][j] + b2[jc+d0+j], 0.f);
    }
    __syncthreads();
    // ---- layer 3 partial: facc += relu(h2chunk) @ W3[jc:jc+64, :] ----
    for (int k4=0; k4<64; k4+=4){
      float4 aa[4], ww[4];
      #pragma unroll
      for(int i=0;i<4;i++) aa[i] = *(const float4*)&h2s[prow+i][k4];
      #pragma unroll
      for(int kk=0;kk<4;kk++) ww[kk] = *(const float4*)&W3[(jc+k4+kk)*DD + d0];
      #pragma unroll
      for(int kk=0;kk<4;kk++){
        #pragma unroll
        for(int i=0;i<4;i++){
          float av = ((const float*)&aa[i])[kk];
          facc[i][0]=fmaf(av, ww[kk].x, facc[i][0]);
          facc[i][1]=fmaf(av, ww[kk].y, facc[i][1]);
          facc[i][2]=fmaf(av, ww[kk].z, facc[i][2]);
          facc[i][3]=fmaf(av, ww[kk].w, facc[i][3]);
        }
      }
    }
  }

  // epilogue: +b3, key-transform, atomic segment max
  #pragma unroll
  for(int i=0;i<4;i++){
    unsigned r = r_s[prow+i];
    unsigned baseo = r*64u + (unsigned)d0;
    #pragma unroll
    for(int j=0;j<4;j++){
      atomicMax(&pooled[baseo + j], fkey(facc[i][j] + b3[d0+j]));
    }
  }
}

extern "C" void kernel_launch(void* const* d_in, const int* in_sizes, int n_in,
                              void* d_out, int out_size, void* d_ws, size_t ws_size,
                              hipStream_t stream){
  const float* pt = (const float*)d_in[0];
  const int*   xy = (const int*)d_in[1];
  const float* W1 = (const float*)d_in[2];
  const float* b1 = (const float*)d_in[3];
  const float* W2 = (const float*)d_in[4];
  const float* b2 = (const float*)d_in[5];
  const float* W3 = (const float*)d_in[6];
  const float* b3 = (const float*)d_in[7];
  float* out = (float*)d_out;

  int M = out_size / 67;               // out = unq (M*3) ++ pooled (M*64)
  int n_pooled = M * 64;

  unsigned* flags = (unsigned*)d_ws;
  unsigned* rank  = flags + NCELL;
  unsigned* bsum  = rank + NCELL;
  unsigned* pooled = (unsigned*)(out + 3*(size_t)M);

  k_clear        <<<NCELL/256, 256, 0, stream>>>(flags);
  k_scatter_flags<<<(NPTS+255)/256, 256, 0, stream>>>(xy, flags);
  k_scan         <<<SCAN_BLK, 256, 0, stream>>>(flags, rank, bsum);
  k_scan_bsum    <<<1, 1024, 0, stream>>>(bsum);
  k_emit_unq     <<<NCELL/256, 256, 0, stream>>>(flags, rank, bsum, out);
  k_init_pooled  <<<2048, 256, 0, stream>>>(pooled, n_pooled);
  k_mlp_scatter  <<<NPTS/64, 256, 0, stream>>>(pt, xy, W1, b1, W2, b2, W3, b3, rank, pooled);
  k_decode       <<<2048, 256, 0, stream>>>(pooled, n_pooled);
}

// Round 2
// 638.502 us; speedup vs baseline: 1.1065x; 1.1065x over previous
//
#include <hip/hip_runtime.h>
#include <hip/hip_bf16.h>

#define GRIDW 480
#define CELLS_PER_B (GRIDW*GRIDW)       // 230400
#define NCELL (4*CELLS_PER_B)           // 921600
#define NPTS  400000
#define NPB   100000
#define H1D 128
#define H2D 256
#define DD 64
#define SCAN_BLK 900                    // NCELL / 1024

typedef unsigned short u16;
typedef __attribute__((ext_vector_type(8))) short bf16x8;
typedef __attribute__((ext_vector_type(4))) short s16x4;
typedef __attribute__((ext_vector_type(4))) float f32x4;

// order-preserving float->uint key (max over keys == max over floats)
static __device__ __forceinline__ unsigned fkey(float f){
  unsigned u = __float_as_uint(f);
  return (u & 0x80000000u) ? ~u : (u | 0x80000000u);
}
static __device__ __forceinline__ float fdec(unsigned k){
  unsigned u = (k & 0x80000000u) ? (k ^ 0x80000000u) : ~k;
  return __uint_as_float(u);
}
// float -> bf16 bits, round-nearest-even (finite inputs)
static __device__ __forceinline__ u16 f2bf(float f){
  unsigned u = __float_as_uint(f);
  unsigned r = u + 0x7FFFu + ((u>>16)&1u);
  return (u16)(r>>16);
}

__global__ void k_clear(unsigned* __restrict__ flags){
  int i = blockIdx.x*256 + threadIdx.x;
  if (i < NCELL) flags[i] = 0u;
}

__global__ void k_scatter_flags(const int* __restrict__ xy, unsigned* __restrict__ flags){
  int p = blockIdx.x*256 + threadIdx.x;
  if (p >= NPTS) return;
  int b = p / NPB;
  int x = xy[2*p], y = xy[2*p+1];
  flags[(b*GRIDW + x)*GRIDW + y] = 1u;
}

// 1024 cells per block: per-thread 4 cells, block exclusive scan
__global__ void k_scan(const unsigned* __restrict__ flags, unsigned* __restrict__ rank,
                       unsigned* __restrict__ bsum){
  __shared__ unsigned sh[256];
  int tid = threadIdx.x;
  int base = blockIdx.x*1024 + tid*4;
  unsigned v0=flags[base], v1=flags[base+1], v2=flags[base+2], v3=flags[base+3];
  unsigned s = v0+v1+v2+v3;
  sh[tid]=s; __syncthreads();
  for (int off=1; off<256; off<<=1){
    unsigned t = (tid>=off) ? sh[tid-off] : 0u;
    __syncthreads();
    sh[tid] += t;
    __syncthreads();
  }
  unsigned excl = sh[tid]-s;
  if (tid==255) bsum[blockIdx.x] = sh[255];
  rank[base]   = excl;
  rank[base+1] = excl+v0;
  rank[base+2] = excl+v0+v1;
  rank[base+3] = excl+v0+v1+v2;
}

__global__ void k_scan_bsum(unsigned* __restrict__ bsum){
  __shared__ unsigned sh[1024];
  int tid = threadIdx.x;
  unsigned v = (tid<SCAN_BLK) ? bsum[tid] : 0u;
  sh[tid]=v; __syncthreads();
  for (int off=1; off<1024; off<<=1){
    unsigned t = (tid>=off) ? sh[tid-off] : 0u;
    __syncthreads();
    sh[tid] += t;
    __syncthreads();
  }
  if (tid<SCAN_BLK) bsum[tid] = sh[tid]-v;
}

__global__ void k_emit_unq(const unsigned* __restrict__ flags, unsigned* __restrict__ rank,
                           const unsigned* __restrict__ bsum, float* __restrict__ out){
  int i = blockIdx.x*256 + threadIdx.x;
  if (i >= NCELL) return;
  unsigned r = rank[i] + bsum[i>>10];
  rank[i] = r;                       // finalize global rank for the MLP pass
  if (flags[i]){
    int b = i / CELLS_PER_B;
    int rem = i - b*CELLS_PER_B;
    int x = rem / GRIDW;
    int y = rem - x*GRIDW;
    float* o = out + 3u*r;           // unq written as floats (harness reads f32)
    o[0]=(float)b; o[1]=(float)x; o[2]=(float)y;
  }
}

__global__ void k_init_pooled(unsigned* __restrict__ pooled, int n){
  for (int i = blockIdx.x*256+threadIdx.x; i < n; i += gridDim.x*256)
    pooled[i] = 0u;                  // fkey domain minimum
}

__global__ void k_decode(unsigned* __restrict__ pooled, int n){
  for (int i = blockIdx.x*256+threadIdx.x; i < n; i += gridDim.x*256)
    ((float*)pooled)[i] = fdec(pooled[i]);
}

// Pack W2 (128x256) and W3 (256x64) into bf16 MFMA-fragment order:
// bp[((n*KO + ko)*16 + c)*8 + j] = W[(ko*8+j)*N + n*16 + c]
__global__ void k_pack(const float* __restrict__ W2, const float* __restrict__ W3,
                       u16* __restrict__ bp2, u16* __restrict__ bp3){
  int e = blockIdx.x*256 + threadIdx.x;
  if (e < 32768){
    int j = e & 7, c = (e>>3)&15, ko = (e>>7)&15, n = e>>11;   // KO2=16, NT2=16
    bp2[e] = f2bf(W2[(ko*8+j)*H2D + n*16 + c]);
  } else {
    int e3 = e - 32768;
    if (e3 < 16384){
      int j = e3 & 7, c = (e3>>3)&15, ko = (e3>>7)&31, n = e3>>12; // KO3=32, NT3=4
      bp3[e3] = f2bf(W3[(ko*8+j)*DD + n*16 + c]);
    }
  }
}

// Fused MLP with bf16 MFMA for layers 2/3 + atomic segment-max scatter.
// 256 threads = 4 waves, 64 points/block.
// Swapped-operand mfma(Wfrag, hfrag) -> output transposed (cols = points):
//   h2 LDS writes are 8B-contiguous, epilogue atomics indexed by point rank.
__global__ __launch_bounds__(256,4) void k_mlp_mfma(
    const float* __restrict__ pt, const int* __restrict__ xy,
    const float* __restrict__ W1, const float* __restrict__ b1,
    const u16* __restrict__ bp2, const float* __restrict__ b2,
    const u16* __restrict__ bp3, const float* __restrict__ b3,
    const unsigned* __restrict__ rank, unsigned* __restrict__ pooled)
{
  __shared__ __attribute__((aligned(16))) u16 h1s[64*128];     // 16 KB, XOR-swizzled
  __shared__ __attribute__((aligned(16))) u16 h2s[2][64*64];   // 2x8 KB, XOR-swizzled
  __shared__ float    in_s[64][3];
  __shared__ unsigned r_s[64];

  const int tid  = threadIdx.x;
  const int lane = tid & 63;
  const int w    = tid >> 6;          // wave 0..3
  const int g    = lane >> 4;         // lane group 0..3
  const int p    = lane & 15;         // lane-in-group
  const int wn   = w & 1;             // col-pair selector
  const int wp   = w >> 1;            // point-pair selector
  const int p0g  = blockIdx.x * 64;

  if (tid < 64){
    int pg = p0g + tid;
    int b = pg / NPB;
    int x = xy[2*pg], y = xy[2*pg+1];
    r_s[tid] = rank[(b*GRIDW+x)*GRIDW + y];
    in_s[tid][0]=pt[pg*3+0]; in_s[tid][1]=pt[pg*3+1]; in_s[tid][2]=pt[pg*3+2];
  }
  __syncthreads();

  // ---- layer 1 (fp32 VALU, tiny): h1[64][128] -> bf16 LDS, swizzled ----
  #pragma unroll
  for (int q=0; q<4; ++q){
    int u = q*256 + tid;
    int row = u >> 4, oct = u & 15;
    float x0=in_s[row][0], x1=in_s[row][1], x2=in_s[row][2];
    bf16x8 ov;
    #pragma unroll
    for (int jj=0; jj<8; ++jj){
      int j = oct*8 + jj;
      float v = b1[j] + x0*W1[j] + x1*W1[H1D+j] + x2*W1[2*H1D+j];
      ov[jj] = (short)f2bf(fmaxf(v, 0.f));
    }
    unsigned byte = ((unsigned)row<<8) + (unsigned)oct*16u;
    byte ^= (unsigned)(row&7) << 4;
    *(bf16x8*)((char*)h1s + byte) = ov;
  }
  __syncthreads();

  // ---- hoist this wave's h1 A(B)-fragments: 2 point-tiles x 4 K-steps ----
  bf16x8 hf[2][4];
  #pragma unroll
  for (int pp=0; pp<2; ++pp){
    int row = (2*wp+pp)*16 + p;
    #pragma unroll
    for (int t=0; t<4; ++t){
      unsigned byte = ((unsigned)row<<8) + (unsigned)t*64u + (unsigned)g*16u;
      byte ^= (unsigned)(row&7) << 4;
      hf[pp][t] = *(const bf16x8*)((const char*)h1s + byte);
    }
  }

  f32x4 acc3[2][2];
  #pragma unroll
  for (int a=0;a<2;a++){
    #pragma unroll
    for (int b=0;b<2;b++){ acc3[a][b][0]=0.f; acc3[a][b][1]=0.f; acc3[a][b][2]=0.f; acc3[a][b][3]=0.f; }
  }

  // ---- chunk loop over h2 columns (4 x 64) ----
  for (int c=0; c<4; ++c){
    // layer 2: this wave's 2 n-tiles x 2 pt-tiles of chunk c, K=128
    f32x4 acc2[2][2];
    #pragma unroll
    for (int a=0;a<2;a++){
      #pragma unroll
      for (int b=0;b<2;b++){ acc2[a][b][0]=0.f; acc2[a][b][1]=0.f; acc2[a][b][2]=0.f; acc2[a][b][3]=0.f; }
    }
    #pragma unroll
    for (int t=0; t<4; ++t){
      bf16x8 wf[2];
      #pragma unroll
      for (int nn=0; nn<2; ++nn){
        int ngl = c*4 + 2*wn + nn;
        wf[nn] = *(const bf16x8*)(bp2 + (((ngl*16 + t*4 + g)*16) + p)*8);
      }
      #pragma unroll
      for (int nn=0; nn<2; ++nn){
        #pragma unroll
        for (int pp=0; pp<2; ++pp)
          acc2[nn][pp] = __builtin_amdgcn_mfma_f32_16x16x32_bf16(wf[nn], hf[pp][t], acc2[nn][pp], 0, 0, 0);
      }
    }
    // bias+relu+cvt, write h2 chunk (transposed D: rows=W2 cols, cols=points)
    u16* h2 = h2s[c & 1];
    #pragma unroll
    for (int nn=0; nn<2; ++nn){
      int nb = (2*wn+nn)*16 + g*4;             // ncol within chunk
      f32x4 bb = *(const f32x4*)&b2[c*64 + nb];
      #pragma unroll
      for (int pp=0; pp<2; ++pp){
        int point = (2*wp+pp)*16 + p;
        s16x4 o;
        #pragma unroll
        for (int i=0;i<4;i++) o[i] = (short)f2bf(fmaxf(acc2[nn][pp][i] + bb[i], 0.f));
        unsigned byte = (unsigned)point*128u + (unsigned)nb*2u;
        byte ^= (unsigned)(point&7) << 4;
        *(s16x4*)((char*)h2 + byte) = o;
      }
    }
    __syncthreads();
    // layer 3 partial: K-steps s = c*2 + {0,1}
    #pragma unroll
    for (int t2=0; t2<2; ++t2){
      int s = c*2 + t2;
      bf16x8 w3f[2], h2f[2];
      #pragma unroll
      for (int dn=0; dn<2; ++dn){
        int dt = 2*wn + dn;
        w3f[dn] = *(const bf16x8*)(bp3 + (((dt*32 + s*4 + g)*16) + p)*8);
      }
      #pragma unroll
      for (int pp=0; pp<2; ++pp){
        int point = (2*wp+pp)*16 + p;
        unsigned byte = (unsigned)point*128u + (unsigned)t2*64u + (unsigned)g*16u;
        byte ^= (unsigned)(point&7) << 4;
        h2f[pp] = *(const bf16x8*)((const char*)h2 + byte);
      }
      #pragma unroll
      for (int dn=0; dn<2; ++dn){
        #pragma unroll
        for (int pp=0; pp<2; ++pp)
          acc3[dn][pp] = __builtin_amdgcn_mfma_f32_16x16x32_bf16(w3f[dn], h2f[pp], acc3[dn][pp], 0, 0, 0);
      }
    }
  }

  // ---- epilogue: +b3, key-transform, atomic segment max ----
  #pragma unroll
  for (int dn=0; dn<2; ++dn){
    int db = (2*wn+dn)*16 + g*4;
    f32x4 b3v = *(const f32x4*)&b3[db];
    #pragma unroll
    for (int pp=0; pp<2; ++pp){
      int point = (2*wp+pp)*16 + p;
      unsigned base = r_s[point]*64u + (unsigned)db;
      #pragma unroll
      for (int i=0;i<4;i++)
        atomicMax(&pooled[base + i], fkey(acc3[dn][pp][i] + b3v[i]));
    }
  }
}

extern "C" void kernel_launch(void* const* d_in, const int* in_sizes, int n_in,
                              void* d_out, int out_size, void* d_ws, size_t ws_size,
                              hipStream_t stream){
  const float* pt = (const float*)d_in[0];
  const int*   xy = (const int*)d_in[1];
  const float* W1 = (const float*)d_in[2];
  const float* b1 = (const float*)d_in[3];
  const float* W2 = (const float*)d_in[4];
  const float* b2 = (const float*)d_in[5];
  const float* W3 = (const float*)d_in[6];
  const float* b3 = (const float*)d_in[7];
  float* out = (float*)d_out;

  int M = out_size / 67;               // out = unq (M*3) ++ pooled (M*64)
  int n_pooled = M * 64;

  unsigned* flags = (unsigned*)d_ws;
  unsigned* rank  = flags + NCELL;
  unsigned* bsum  = rank + NCELL;
  u16* bp2 = (u16*)(d_ws) + (2*NCELL + 1024)*2;   // u16 offset: (2*NCELL+1024) u32s
  u16* bp3 = bp2 + 32768;
  unsigned* pooled = (unsigned*)(out + 3*(size_t)M);

  k_clear        <<<NCELL/256, 256, 0, stream>>>(flags);
  k_scatter_flags<<<(NPTS+255)/256, 256, 0, stream>>>(xy, flags);
  k_pack         <<<192, 256, 0, stream>>>(W2, W3, bp2, bp3);
  k_scan         <<<SCAN_BLK, 256, 0, stream>>>(flags, rank, bsum);
  k_scan_bsum    <<<1, 1024, 0, stream>>>(bsum);
  k_emit_unq     <<<NCELL/256, 256, 0, stream>>>(flags, rank, bsum, out);
  k_init_pooled  <<<2048, 256, 0, stream>>>(pooled, n_pooled);
  k_mlp_mfma     <<<NPTS/64, 256, 0, stream>>>(pt, xy, W1, b1, bp2, b2, bp3, b3, rank, pooled);
  k_decode       <<<2048, 256, 0, stream>>>(pooled, n_pooled);
}

// Round 4
// 335.460 us; speedup vs baseline: 2.1061x; 1.9034x over previous
//
#include <hip/hip_runtime.h>
#include <hip/hip_bf16.h>

#define GRIDW 480
#define CELLS_PER_B (GRIDW*GRIDW)       // 230400
#define NCELL (4*CELLS_PER_B)           // 921600
#define NPTS  400000
#define NPB   100000
#define H1D 128
#define H2D 256
#define DD 64
#define SCAN_BLK 900                    // NCELL / 1024

typedef unsigned short u16;
typedef __attribute__((ext_vector_type(8))) short bf16x8;
typedef __attribute__((ext_vector_type(4))) short s16x4;
typedef __attribute__((ext_vector_type(4))) float f32x4;

// order-preserving float->uint key (fallback path only)
static __device__ __forceinline__ unsigned fkey(float f){
  unsigned u = __float_as_uint(f);
  return (u & 0x80000000u) ? ~u : (u | 0x80000000u);
}
static __device__ __forceinline__ float fdec(unsigned k){
  unsigned u = (k & 0x80000000u) ? (k ^ 0x80000000u) : ~k;
  return __uint_as_float(u);
}
// float -> bf16 bits, round-nearest-even (finite inputs)
static __device__ __forceinline__ u16 f2bf(float f){
  unsigned u = __float_as_uint(f);
  unsigned r = u + 0x7FFFu + ((u>>16)&1u);
  return (u16)(r>>16);
}

__global__ void k_clear(unsigned* __restrict__ counts){
  int i = blockIdx.x*256 + threadIdx.x;
  if (i < NCELL) counts[i] = 0u;
}

__global__ void k_count(const int* __restrict__ xy, unsigned* __restrict__ counts){
  int p = blockIdx.x*256 + threadIdx.x;
  if (p >= NPTS) return;
  int b = p / NPB;
  int x = xy[2*p], y = xy[2*p+1];
  atomicAdd(&counts[(b*GRIDW + x)*GRIDW + y], 1u);
}

// dual scan: rankF = excl prefix of (count>0), rankC = excl prefix of count
__global__ void k_scan2(const unsigned* __restrict__ counts,
                        unsigned* __restrict__ rankF, unsigned* __restrict__ rankC,
                        unsigned* __restrict__ bsumF, unsigned* __restrict__ bsumC){
  __shared__ unsigned shF[256], shC[256];
  int tid = threadIdx.x;
  int base = blockIdx.x*1024 + tid*4;
  unsigned c0=counts[base], c1=counts[base+1], c2=counts[base+2], c3=counts[base+3];
  unsigned f0=c0?1u:0u, f1=c1?1u:0u, f2=c2?1u:0u, f3=c3?1u:0u;
  unsigned sF=f0+f1+f2+f3, sC=c0+c1+c2+c3;
  shF[tid]=sF; shC[tid]=sC; __syncthreads();
  for (int off=1; off<256; off<<=1){
    unsigned tF = (tid>=off) ? shF[tid-off] : 0u;
    unsigned tC = (tid>=off) ? shC[tid-off] : 0u;
    __syncthreads();
    shF[tid] += tF; shC[tid] += tC;
    __syncthreads();
  }
  unsigned eF = shF[tid]-sF, eC = shC[tid]-sC;
  if (tid==255){ bsumF[blockIdx.x]=shF[255]; bsumC[blockIdx.x]=shC[255]; }
  rankF[base]=eF; rankF[base+1]=eF+f0; rankF[base+2]=eF+f0+f1; rankF[base+3]=eF+f0+f1+f2;
  rankC[base]=eC; rankC[base+1]=eC+c0; rankC[base+2]=eC+c0+c1; rankC[base+3]=eC+c0+c1+c2;
}

__global__ void k_scan_bsum2(unsigned* __restrict__ bsumF, unsigned* __restrict__ bsumC){
  __shared__ unsigned shF[1024], shC[1024];
  int tid = threadIdx.x;
  unsigned vF = (tid<SCAN_BLK) ? bsumF[tid] : 0u;
  unsigned vC = (tid<SCAN_BLK) ? bsumC[tid] : 0u;
  shF[tid]=vF; shC[tid]=vC; __syncthreads();
  for (int off=1; off<1024; off<<=1){
    unsigned tF = (tid>=off) ? shF[tid-off] : 0u;
    unsigned tC = (tid>=off) ? shC[tid-off] : 0u;
    __syncthreads();
    shF[tid] += tF; shC[tid] += tC;
    __syncthreads();
  }
  if (tid<SCAN_BLK){ bsumF[tid]=shF[tid]-vF; bsumC[tid]=shC[tid]-vC; }
}

// finalize ranks, emit unq, and (sorted path) per-voxel start/count
__global__ void k_emit2(const unsigned* __restrict__ counts,
                        unsigned* __restrict__ rankF, unsigned* __restrict__ rankC,
                        const unsigned* __restrict__ bsumF, const unsigned* __restrict__ bsumC,
                        float* __restrict__ out,
                        unsigned* __restrict__ vstart, unsigned* __restrict__ vcnt){
  int i = blockIdx.x*256 + threadIdx.x;
  if (i >= NCELL) return;
  unsigned rF = rankF[i] + bsumF[i>>10];
  unsigned rC = rankC[i] + bsumC[i>>10];
  rankF[i] = rF;                      // fallback path: per-cell output rank
  rankC[i] = rC;                      // sorted path: per-cell scatter cursor
  unsigned c = counts[i];
  if (c){
    int b = i / CELLS_PER_B;
    int rem = i - b*CELLS_PER_B;
    int x = rem / GRIDW;
    int y = rem - x*GRIDW;
    float* o = out + 3u*rF;           // unq written as floats (harness reads f32)
    o[0]=(float)b; o[1]=(float)x; o[2]=(float)y;
    if (vstart){ vstart[rF] = rC; vcnt[rF] = c; }
  }
}

__global__ void k_scatterp(const int* __restrict__ xy, unsigned* __restrict__ cursor,
                           unsigned* __restrict__ perm){
  int p = blockIdx.x*256 + threadIdx.x;
  if (p >= NPTS) return;
  int b = p / NPB;
  int x = xy[2*p], y = xy[2*p+1];
  unsigned slot = atomicAdd(&cursor[(b*GRIDW+x)*GRIDW + y], 1u);
  perm[slot] = (unsigned)p;
}

__global__ void k_init_pooled(unsigned* __restrict__ pooled, int n){
  for (int i = blockIdx.x*256+threadIdx.x; i < n; i += gridDim.x*256)
    pooled[i] = 0u;                  // fkey domain minimum
}

__global__ void k_decode(unsigned* __restrict__ pooled, int n){
  for (int i = blockIdx.x*256+threadIdx.x; i < n; i += gridDim.x*256)
    ((float*)pooled)[i] = fdec(pooled[i]);
}

// Pack W2 (128x256) and W3 (256x64) into bf16 MFMA-fragment order:
// bp[((n*KO + ko)*16 + c)*8 + j] = W[(ko*8+j)*N + n*16 + c]
__global__ void k_pack(const float* __restrict__ W2, const float* __restrict__ W3,
                       u16* __restrict__ bp2, u16* __restrict__ bp3){
  int e = blockIdx.x*256 + threadIdx.x;
  if (e < 32768){
    int j = e & 7, c = (e>>3)&15, ko = (e>>7)&15, n = e>>11;   // KO2=16, NT2=16
    bp2[e] = f2bf(W2[(ko*8+j)*H2D + n*16 + c]);
  } else {
    int e3 = e - 32768;
    if (e3 < 16384){
      int j = e3 & 7, c = (e3>>3)&15, ko = (e3>>7)&31, n = e3>>12; // KO3=32, NT3=4
      bp3[e3] = f2bf(W3[(ko*8+j)*DD + n*16 + c]);
    }
  }
}

// Fused MLP with bf16 MFMA for layers 2/3. 256 threads = 4 waves, 64 points.
// SORTED: plain bf16 feat stores. !SORTED: fkey atomicMax epilogue (fallback).
template<bool SORTED>
__global__ __launch_bounds__(256,4) void k_mlp(
    const float* __restrict__ pt, const int* __restrict__ xy,
    const float* __restrict__ W1, const float* __restrict__ b1,
    const u16* __restrict__ bp2, const float* __restrict__ b2,
    const u16* __restrict__ bp3, const float* __restrict__ b3,
    const unsigned* __restrict__ rank, unsigned* __restrict__ pooled,
    u16* __restrict__ feat)
{
  __shared__ __attribute__((aligned(16))) u16 h1s[64*128];     // 16 KB, XOR-swizzled
  __shared__ __attribute__((aligned(16))) u16 h2s[2][64*64];   // 2x8 KB, XOR-swizzled
  __shared__ float    in_s[64][3];
  __shared__ unsigned r_s[64];

  const int tid  = threadIdx.x;
  const int lane = tid & 63;
  const int w    = tid >> 6;          // wave 0..3
  const int g    = lane >> 4;         // lane group 0..3
  const int p    = lane & 15;         // lane-in-group
  const int wn   = w & 1;             // col-pair selector
  const int wp   = w >> 1;            // point-pair selector
  const int p0g  = blockIdx.x * 64;

  if (tid < 64){
    int pg = p0g + tid;
    if constexpr (!SORTED){
      int b = pg / NPB;
      int x = xy[2*pg], y = xy[2*pg+1];
      r_s[tid] = rank[(b*GRIDW+x)*GRIDW + y];
    }
    in_s[tid][0]=pt[pg*3+0]; in_s[tid][1]=pt[pg*3+1]; in_s[tid][2]=pt[pg*3+2];
  }
  __syncthreads();

  // ---- layer 1 (fp32 VALU, tiny): h1[64][128] -> bf16 LDS, swizzled ----
  #pragma unroll
  for (int q=0; q<4; ++q){
    int u = q*256 + tid;
    int row = u >> 4, oct = u & 15;
    float x0=in_s[row][0], x1=in_s[row][1], x2=in_s[row][2];
    bf16x8 ov;
    #pragma unroll
    for (int jj=0; jj<8; ++jj){
      int j = oct*8 + jj;
      float v = b1[j] + x0*W1[j] + x1*W1[H1D+j] + x2*W1[2*H1D+j];
      ov[jj] = (short)f2bf(fmaxf(v, 0.f));
    }
    unsigned byte = ((unsigned)row<<8) + (unsigned)oct*16u;
    byte ^= (unsigned)(row&7) << 4;
    *(bf16x8*)((char*)h1s + byte) = ov;
  }
  __syncthreads();

  // ---- hoist this wave's h1 fragments: 2 point-tiles x 4 K-steps ----
  bf16x8 hf[2][4];
  #pragma unroll
  for (int pp=0; pp<2; ++pp){
    int row = (2*wp+pp)*16 + p;
    #pragma unroll
    for (int t=0; t<4; ++t){
      unsigned byte = ((unsigned)row<<8) + (unsigned)t*64u + (unsigned)g*16u;
      byte ^= (unsigned)(row&7) << 4;
      hf[pp][t] = *(const bf16x8*)((const char*)h1s + byte);
    }
  }

  f32x4 acc3[2][2];
  #pragma unroll
  for (int a=0;a<2;a++){
    #pragma unroll
    for (int b=0;b<2;b++){ acc3[a][b][0]=0.f; acc3[a][b][1]=0.f; acc3[a][b][2]=0.f; acc3[a][b][3]=0.f; }
  }

  // ---- chunk loop over h2 columns (4 x 64) ----
  for (int c=0; c<4; ++c){
    f32x4 acc2[2][2];
    #pragma unroll
    for (int a=0;a<2;a++){
      #pragma unroll
      for (int b=0;b<2;b++){ acc2[a][b][0]=0.f; acc2[a][b][1]=0.f; acc2[a][b][2]=0.f; acc2[a][b][3]=0.f; }
    }
    #pragma unroll
    for (int t=0; t<4; ++t){
      bf16x8 wf[2];
      #pragma unroll
      for (int nn=0; nn<2; ++nn){
        int ngl = c*4 + 2*wn + nn;
        wf[nn] = *(const bf16x8*)(bp2 + (((ngl*16 + t*4 + g)*16) + p)*8);
      }
      #pragma unroll
      for (int nn=0; nn<2; ++nn){
        #pragma unroll
        for (int pp=0; pp<2; ++pp)
          acc2[nn][pp] = __builtin_amdgcn_mfma_f32_16x16x32_bf16(wf[nn], hf[pp][t], acc2[nn][pp], 0, 0, 0);
      }
    }
    u16* h2 = h2s[c & 1];
    #pragma unroll
    for (int nn=0; nn<2; ++nn){
      int nb = (2*wn+nn)*16 + g*4;             // ncol within chunk
      f32x4 bb = *(const f32x4*)&b2[c*64 + nb];
      #pragma unroll
      for (int pp=0; pp<2; ++pp){
        int point = (2*wp+pp)*16 + p;
        s16x4 o;
        #pragma unroll
        for (int i=0;i<4;i++) o[i] = (short)f2bf(fmaxf(acc2[nn][pp][i] + bb[i], 0.f));
        unsigned byte = (unsigned)point*128u + (unsigned)nb*2u;
        byte ^= (unsigned)(point&7) << 4;
        *(s16x4*)((char*)h2 + byte) = o;
      }
    }
    __syncthreads();
    #pragma unroll
    for (int t2=0; t2<2; ++t2){
      int s = c*2 + t2;
      bf16x8 w3f[2], h2f[2];
      #pragma unroll
      for (int dn=0; dn<2; ++dn){
        int dt = 2*wn + dn;
        w3f[dn] = *(const bf16x8*)(bp3 + (((dt*32 + s*4 + g)*16) + p)*8);
      }
      #pragma unroll
      for (int pp=0; pp<2; ++pp){
        int point = (2*wp+pp)*16 + p;
        unsigned byte = (unsigned)point*128u + (unsigned)t2*64u + (unsigned)g*16u;
        byte ^= (unsigned)(point&7) << 4;
        h2f[pp] = *(const bf16x8*)((const char*)h2 + byte);
      }
      #pragma unroll
      for (int dn=0; dn<2; ++dn){
        #pragma unroll
        for (int pp=0; pp<2; ++pp)
          acc3[dn][pp] = __builtin_amdgcn_mfma_f32_16x16x32_bf16(w3f[dn], h2f[pp], acc3[dn][pp], 0, 0, 0);
      }
    }
  }

  // ---- epilogue ----
  #pragma unroll
  for (int dn=0; dn<2; ++dn){
    int db = (2*wn+dn)*16 + g*4;
    f32x4 b3v = *(const f32x4*)&b3[db];
    #pragma unroll
    for (int pp=0; pp<2; ++pp){
      int point = (2*wp+pp)*16 + p;
      if constexpr (SORTED){
        s16x4 o;
        #pragma unroll
        for (int i=0;i<4;i++) o[i] = (short)f2bf(acc3[dn][pp][i] + b3v[i]);
        *(s16x4*)&feat[(size_t)(p0g+point)*64u + (unsigned)db] = o;
      } else {
        unsigned base = r_s[point]*64u + (unsigned)db;
        #pragma unroll
        for (int i=0;i<4;i++)
          atomicMax(&pooled[base + i], fkey(acc3[dn][pp][i] + b3v[i]));
      }
    }
  }
}

// gather-max pooling: 4 voxels/block, thread = (voxel, channel)
__global__ __launch_bounds__(256) void k_pool(
    const unsigned* __restrict__ vstart, const unsigned* __restrict__ vcnt,
    const unsigned* __restrict__ perm, const u16* __restrict__ feat,
    float* __restrict__ pooled, int M){
  int vi = blockIdx.x*4 + (threadIdx.x>>6);
  int ch = threadIdx.x & 63;
  if (vi >= M) return;
  unsigned s = vstart[vi], c = vcnt[vi];
  unsigned p0 = perm[s];
  float m = __uint_as_float(((unsigned)feat[(size_t)p0*64u + ch]) << 16);
  for (unsigned i=1; i<c; ++i){
    unsigned p = perm[s+i];
    float v = __uint_as_float(((unsigned)feat[(size_t)p*64u + ch]) << 16);
    m = fmaxf(m, v);
  }
  pooled[(size_t)vi*64u + ch] = m;
}

extern "C" void kernel_launch(void* const* d_in, const int* in_sizes, int n_in,
                              void* d_out, int out_size, void* d_ws, size_t ws_size,
                              hipStream_t stream){
  const float* pt = (const float*)d_in[0];
  const int*   xy = (const int*)d_in[1];
  const float* W1 = (const float*)d_in[2];
  const float* b1 = (const float*)d_in[3];
  const float* W2 = (const float*)d_in[4];
  const float* b2 = (const float*)d_in[5];
  const float* W3 = (const float*)d_in[6];
  const float* b3 = (const float*)d_in[7];
  float* out = (float*)d_out;

  int M = out_size / 67;               // out = unq (M*3) ++ pooled (M*64)

  // workspace layout (u32 units)
  unsigned* counts = (unsigned*)d_ws;
  unsigned* rankF  = counts + NCELL;
  unsigned* rankC  = rankF + NCELL;
  unsigned* bsumF  = rankC + NCELL;
  unsigned* bsumC  = bsumF + 1024;
  unsigned* vstart = bsumC + 1024;
  unsigned* vcnt   = vstart + NPTS;
  unsigned* perm   = vcnt + NPTS;
  u16* bp2 = (u16*)(perm + NPTS);
  u16* bp3 = bp2 + 32768;
  u16* feat = bp3 + 16384;
  size_t need = (size_t)((char*)(feat + (size_t)NPTS*64) - (char*)d_ws);

  if (ws_size >= need){
    // ---- sorted two-phase path (no pooled-atomics) ----
    k_clear      <<<NCELL/256, 256, 0, stream>>>(counts);
    k_count      <<<(NPTS+255)/256, 256, 0, stream>>>(xy, counts);
    k_pack       <<<192, 256, 0, stream>>>(W2, W3, bp2, bp3);
    k_scan2      <<<SCAN_BLK, 256, 0, stream>>>(counts, rankF, rankC, bsumF, bsumC);
    k_scan_bsum2 <<<1, 1024, 0, stream>>>(bsumF, bsumC);
    k_emit2      <<<NCELL/256, 256, 0, stream>>>(counts, rankF, rankC, bsumF, bsumC,
                                                 out, vstart, vcnt);
    k_scatterp   <<<(NPTS+255)/256, 256, 0, stream>>>(xy, rankC, perm);
    k_mlp<true>  <<<NPTS/64, 256, 0, stream>>>(pt, xy, W1, b1, bp2, b2, bp3, b3,
                                               nullptr, nullptr, feat);
    k_pool       <<<(M+3)/4, 256, 0, stream>>>(vstart, vcnt, perm, feat,
                                               out + 3*(size_t)M, M);
  } else {
    // ---- fallback: fkey atomicMax path (round-2 behavior) ----
    unsigned* pooled = (unsigned*)(out + 3*(size_t)M);
    int n_pooled = M * 64;
    k_clear      <<<NCELL/256, 256, 0, stream>>>(counts);
    k_count      <<<(NPTS+255)/256, 256, 0, stream>>>(xy, counts);
    k_pack       <<<192, 256, 0, stream>>>(W2, W3, bp2, bp3);
    k_scan2      <<<SCAN_BLK, 256, 0, stream>>>(counts, rankF, rankC, bsumF, bsumC);
    k_scan_bsum2 <<<1, 1024, 0, stream>>>(bsumF, bsumC);
    k_emit2      <<<NCELL/256, 256, 0, stream>>>(counts, rankF, rankC, bsumF, bsumC,
                                                 out, nullptr, nullptr);
    k_init_pooled<<<2048, 256, 0, stream>>>(pooled, n_pooled);
    k_mlp<false> <<<NPTS/64, 256, 0, stream>>>(pt, xy, W1, b1, bp2, b2, bp3, b3,
                                               rankF, pooled, nullptr);
    k_decode     <<<2048, 256, 0, stream>>>(pooled, n_pooled);
  }
}

// Round 5
// 212.500 us; speedup vs baseline: 3.3247x; 1.5786x over previous
//
#include <hip/hip_runtime.h>
#include <hip/hip_bf16.h>

#define GRIDW 480
#define CELLS_PER_B (GRIDW*GRIDW)       // 230400
#define NCELL (4*CELLS_PER_B)           // 921600
#define NPTS  400000
#define NPB   100000
#define H1D 128
#define H2D 256
#define DD 64
#define SCAN_BLK 900                    // NCELL / 1024
#define NTILE 6250                      // NPTS/64
#define NBLK  256                       // persistent blocks (1 per CU)

typedef unsigned short u16;
typedef __attribute__((ext_vector_type(8))) short bf16x8;
typedef __attribute__((ext_vector_type(4))) short s16x4;
typedef __attribute__((ext_vector_type(4))) float f32x4;
typedef __attribute__((ext_vector_type(4))) unsigned u32x4;
typedef __attribute__((ext_vector_type(2))) unsigned u32x2;

// order-preserving float->uint key (fallback path only)
static __device__ __forceinline__ unsigned fkey(float f){
  unsigned u = __float_as_uint(f);
  return (u & 0x80000000u) ? ~u : (u | 0x80000000u);
}
static __device__ __forceinline__ float fdec(unsigned k){
  unsigned u = (k & 0x80000000u) ? (k ^ 0x80000000u) : ~k;
  return __uint_as_float(u);
}
// float -> bf16 bits, round-nearest-even (finite inputs)
static __device__ __forceinline__ u16 f2bf(float f){
  unsigned u = __float_as_uint(f);
  unsigned r = u + 0x7FFFu + ((u>>16)&1u);
  return (u16)(r>>16);
}
// packed 2x f32 -> 2x bf16 in one u32 (low = first operand)
static __device__ __forceinline__ unsigned cvt_pk_bf16(float lo, float hi){
  unsigned r;
  asm("v_cvt_pk_bf16_f32 %0, %1, %2" : "=v"(r) : "v"(lo), "v"(hi));
  return r;
}

__global__ void k_count(const int* __restrict__ xy, unsigned* __restrict__ counts){
  int p = blockIdx.x*256 + threadIdx.x;
  if (p >= NPTS) return;
  int b = p / NPB;
  int x = xy[2*p], y = xy[2*p+1];
  atomicAdd(&counts[(b*GRIDW + x)*GRIDW + y], 1u);
}

// dual scan: rankF = excl prefix of (count>0), rankC = excl prefix of count
__global__ void k_scan2(const unsigned* __restrict__ counts,
                        unsigned* __restrict__ rankF, unsigned* __restrict__ rankC,
                        unsigned* __restrict__ bsumF, unsigned* __restrict__ bsumC){
  __shared__ unsigned shF[256], shC[256];
  int tid = threadIdx.x;
  int base = blockIdx.x*1024 + tid*4;
  unsigned c0=counts[base], c1=counts[base+1], c2=counts[base+2], c3=counts[base+3];
  unsigned f0=c0?1u:0u, f1=c1?1u:0u, f2=c2?1u:0u, f3=c3?1u:0u;
  unsigned sF=f0+f1+f2+f3, sC=c0+c1+c2+c3;
  shF[tid]=sF; shC[tid]=sC; __syncthreads();
  for (int off=1; off<256; off<<=1){
    unsigned tF = (tid>=off) ? shF[tid-off] : 0u;
    unsigned tC = (tid>=off) ? shC[tid-off] : 0u;
    __syncthreads();
    shF[tid] += tF; shC[tid] += tC;
    __syncthreads();
  }
  unsigned eF = shF[tid]-sF, eC = shC[tid]-sC;
  if (tid==255){ bsumF[blockIdx.x]=shF[255]; bsumC[blockIdx.x]=shC[255]; }
  rankF[base]=eF; rankF[base+1]=eF+f0; rankF[base+2]=eF+f0+f1; rankF[base+3]=eF+f0+f1+f2;
  rankC[base]=eC; rankC[base+1]=eC+c0; rankC[base+2]=eC+c0+c1; rankC[base+3]=eC+c0+c1+c2;
}

__global__ void k_scan_bsum2(unsigned* __restrict__ bsumF, unsigned* __restrict__ bsumC){
  __shared__ unsigned shF[1024], shC[1024];
  int tid = threadIdx.x;
  unsigned vF = (tid<SCAN_BLK) ? bsumF[tid] : 0u;
  unsigned vC = (tid<SCAN_BLK) ? bsumC[tid] : 0u;
  shF[tid]=vF; shC[tid]=vC; __syncthreads();
  for (int off=1; off<1024; off<<=1){
    unsigned tF = (tid>=off) ? shF[tid-off] : 0u;
    unsigned tC = (tid>=off) ? shC[tid-off] : 0u;
    __syncthreads();
    shF[tid] += tF; shC[tid] += tC;
    __syncthreads();
  }
  if (tid<SCAN_BLK){ bsumF[tid]=shF[tid]-vF; bsumC[tid]=shC[tid]-vC; }
}

// finalize ranks, emit unq, and (sorted path) per-voxel start/count
__global__ void k_emit2(const unsigned* __restrict__ counts,
                        unsigned* __restrict__ rankF, unsigned* __restrict__ rankC,
                        const unsigned* __restrict__ bsumF, const unsigned* __restrict__ bsumC,
                        float* __restrict__ out,
                        unsigned* __restrict__ vstart, unsigned* __restrict__ vcnt){
  int i = blockIdx.x*256 + threadIdx.x;
  if (i >= NCELL) return;
  unsigned rF = rankF[i] + bsumF[i>>10];
  unsigned rC = rankC[i] + bsumC[i>>10];
  rankF[i] = rF;                      // fallback path: per-cell output rank
  rankC[i] = rC;                      // sorted path: per-cell scatter cursor
  unsigned c = counts[i];
  if (c){
    int b = i / CELLS_PER_B;
    int rem = i - b*CELLS_PER_B;
    int x = rem / GRIDW;
    int y = rem - x*GRIDW;
    float* o = out + 3u*rF;           // unq written as floats (harness reads f32)
    o[0]=(float)b; o[1]=(float)x; o[2]=(float)y;
    if (vstart){ vstart[rF] = rC; vcnt[rF] = c; }
  }
}

__global__ void k_scatterp(const int* __restrict__ xy, unsigned* __restrict__ cursor,
                           unsigned* __restrict__ perm){
  int p = blockIdx.x*256 + threadIdx.x;
  if (p >= NPTS) return;
  int b = p / NPB;
  int x = xy[2*p], y = xy[2*p+1];
  unsigned slot = atomicAdd(&cursor[(b*GRIDW+x)*GRIDW + y], 1u);
  perm[slot] = (unsigned)p;
}

__global__ void k_init_pooled(unsigned* __restrict__ pooled, int n){
  for (int i = blockIdx.x*256+threadIdx.x; i < n; i += gridDim.x*256)
    pooled[i] = 0u;
}

__global__ void k_decode(unsigned* __restrict__ pooled, int n){
  for (int i = blockIdx.x*256+threadIdx.x; i < n; i += gridDim.x*256)
    ((float*)pooled)[i] = fdec(pooled[i]);
}

// Pack W2 (128x256) and W3 (256x64) into bf16 MFMA-fragment order:
// bp[((n*KO + ko)*16 + c)*8 + j] = W[(ko*8+j)*N + n*16 + c]
__global__ void k_pack(const float* __restrict__ W2, const float* __restrict__ W3,
                       u16* __restrict__ bp2, u16* __restrict__ bp3){
  int e = blockIdx.x*256 + threadIdx.x;
  if (e < 32768){
    int j = e & 7, c = (e>>3)&15, ko = (e>>7)&15, n = e>>11;   // KO2=16, NT2=16
    bp2[e] = f2bf(W2[(ko*8+j)*H2D + n*16 + c]);
  } else {
    int e3 = e - 32768;
    if (e3 < 16384){
      int j = e3 & 7, c = (e3>>3)&15, ko = (e3>>7)&31, n = e3>>12; // KO3=32, NT3=4
      bp3[e3] = f2bf(W3[(ko*8+j)*DD + n*16 + c]);
    }
  }
}

// ---------------------------------------------------------------------------
// Persistent fused MLP: 256 blocks (1/CU), 4 waves, ~24 tiles of 64 points.
// All weight fragments register-resident (1 wave/SIMD by VGPR design).
// Epilogue transposes acc3 through LDS -> contiguous 1KB global stores.
// ---------------------------------------------------------------------------
__global__ __launch_bounds__(256,1) void k_mlpp(
    const float* __restrict__ pt,
    const u16* __restrict__ bp2, const u16* __restrict__ bp3,
    const float* __restrict__ W1, const float* __restrict__ b1,
    const float* __restrict__ b2, const float* __restrict__ b3,
    u16* __restrict__ feat)
{
  __shared__ __attribute__((aligned(16))) u16 h1s[64*128];     // 16 KB, swizzled
  __shared__ __attribute__((aligned(16))) u16 h2s[2][64*64];   // 2x8 KB, swizzled
  __shared__ __attribute__((aligned(16))) float in_s[192];

  const int tid  = threadIdx.x;
  const int lane = tid & 63;
  const int w    = tid >> 6;          // wave 0..3
  const int g    = lane >> 4;         // lane group 0..3
  const int p    = lane & 15;         // lane-in-group
  const int wn   = w & 1;             // col-pair selector
  const int wp   = w >> 1;            // point-pair selector
  const int oct  = tid & 15;          // layer-1 channel octet

  // ---- persistent register state -----------------------------------------
  bf16x8 wf2[32];
  #pragma unroll
  for (int c=0;c<4;++c)
    #pragma unroll
    for (int nn=0;nn<2;++nn)
      #pragma unroll
      for (int t=0;t<4;++t){
        int ngl = c*4 + 2*wn + nn;
        wf2[(c*2+nn)*4+t] = *(const bf16x8*)(bp2 + (((ngl*16 + t*4 + g)*16) + p)*8);
      }
  bf16x8 wf3[16];
  #pragma unroll
  for (int c=0;c<4;++c)
    #pragma unroll
    for (int t2=0;t2<2;++t2)
      #pragma unroll
      for (int dn=0;dn<2;++dn){
        int s = c*2+t2, dt = 2*wn+dn;
        wf3[(c*2+t2)*2+dn] = *(const bf16x8*)(bp3 + (((dt*32 + s*4 + g)*16) + p)*8);
      }
  f32x4 W1p[3][2], b1p[2];
  #pragma unroll
  for (int f=0;f<3;++f){
    W1p[f][0] = *(const f32x4*)(W1 + f*H1D + oct*8);
    W1p[f][1] = *(const f32x4*)(W1 + f*H1D + oct*8 + 4);
  }
  b1p[0] = *(const f32x4*)(b1 + oct*8);
  b1p[1] = *(const f32x4*)(b1 + oct*8 + 4);
  f32x4 b2p[4][2];
  #pragma unroll
  for (int c=0;c<4;++c)
    #pragma unroll
    for (int nn=0;nn<2;++nn)
      b2p[c][nn] = *(const f32x4*)(b2 + c*64 + (2*wn+nn)*16 + g*4);
  f32x4 b3p[2];
  #pragma unroll
  for (int dn=0;dn<2;++dn)
    b3p[dn] = *(const f32x4*)(b3 + (2*wn+dn)*16 + g*4);

  // ---- prefetch first tile's points --------------------------------------
  f32x4 pref;
  int tile = blockIdx.x;
  if (tid < 48) pref = *(const f32x4*)(pt + (size_t)tile*192 + tid*4);

  for (; tile < NTILE; tile += NBLK){
    // stage points, then prefetch next tile
    if (tid < 48) *(f32x4*)&in_s[tid*4] = pref;
    __syncthreads();                                   // A
    int nt = tile + NBLK;
    if (nt < NTILE && tid < 48)
      pref = *(const f32x4*)(pt + (size_t)nt*192 + tid*4);

    // ---- layer 1: h1[64][128] -> bf16 LDS (swizzled) ----
    #pragma unroll
    for (int q=0;q<4;++q){
      int row = q*16 + (tid>>4);
      float x0 = in_s[row*3+0], x1 = in_s[row*3+1], x2 = in_s[row*3+2];
      f32x4 a0 = b1p[0], a1 = b1p[1];
      #pragma unroll
      for (int i=0;i<4;++i){
        a0[i] = fmaf(x0, W1p[0][0][i], a0[i]);
        a1[i] = fmaf(x0, W1p[0][1][i], a1[i]);
        a0[i] = fmaf(x1, W1p[1][0][i], a0[i]);
        a1[i] = fmaf(x1, W1p[1][1][i], a1[i]);
        a0[i] = fmaf(x2, W1p[2][0][i], a0[i]);
        a1[i] = fmaf(x2, W1p[2][1][i], a1[i]);
        a0[i] = fmaxf(a0[i], 0.f);
        a1[i] = fmaxf(a1[i], 0.f);
      }
      u32x4 ov;
      ov[0] = cvt_pk_bf16(a0[0], a0[1]);
      ov[1] = cvt_pk_bf16(a0[2], a0[3]);
      ov[2] = cvt_pk_bf16(a1[0], a1[1]);
      ov[3] = cvt_pk_bf16(a1[2], a1[3]);
      unsigned byte = ((unsigned)row<<8) + (unsigned)oct*16u;
      byte ^= (unsigned)(row&7) << 4;
      *(u32x4*)((char*)h1s + byte) = ov;
    }
    __syncthreads();                                   // B

    // ---- hoist this wave's h1 fragments ----
    bf16x8 hf[2][4];
    #pragma unroll
    for (int pp=0;pp<2;++pp){
      int row = (2*wp+pp)*16 + p;
      #pragma unroll
      for (int t=0;t<4;++t){
        unsigned byte = ((unsigned)row<<8) + (unsigned)t*64u + (unsigned)g*16u;
        byte ^= (unsigned)(row&7) << 4;
        hf[pp][t] = *(const bf16x8*)((const char*)h1s + byte);
      }
    }

    f32x4 acc3[2][2];
    #pragma unroll
    for (int a=0;a<2;++a)
      #pragma unroll
      for (int b=0;b<2;++b){ acc3[a][b][0]=0.f; acc3[a][b][1]=0.f; acc3[a][b][2]=0.f; acc3[a][b][3]=0.f; }

    // ---- chunk loop over h2 columns (4 x 64) ----
    #pragma unroll
    for (int c=0;c<4;++c){
      f32x4 acc2[2][2];
      #pragma unroll
      for (int a=0;a<2;++a)
        #pragma unroll
        for (int b=0;b<2;++b){ acc2[a][b][0]=0.f; acc2[a][b][1]=0.f; acc2[a][b][2]=0.f; acc2[a][b][3]=0.f; }
      #pragma unroll
      for (int t=0;t<4;++t)
        #pragma unroll
        for (int nn=0;nn<2;++nn)
          #pragma unroll
          for (int pp=0;pp<2;++pp)
            acc2[nn][pp] = __builtin_amdgcn_mfma_f32_16x16x32_bf16(
                wf2[(c*2+nn)*4+t], hf[pp][t], acc2[nn][pp], 0, 0, 0);
      // bias + relu + cvt -> h2 LDS (transposed D: rows = W2 cols, cols = points)
      u16* h2 = h2s[c & 1];
      #pragma unroll
      for (int nn=0;nn<2;++nn)
        #pragma unroll
        for (int pp=0;pp<2;++pp){
          int point = (2*wp+pp)*16 + p;
          float e0 = fmaxf(acc2[nn][pp][0] + b2p[c][nn][0], 0.f);
          float e1 = fmaxf(acc2[nn][pp][1] + b2p[c][nn][1], 0.f);
          float e2 = fmaxf(acc2[nn][pp][2] + b2p[c][nn][2], 0.f);
          float e3 = fmaxf(acc2[nn][pp][3] + b2p[c][nn][3], 0.f);
          u32x2 o2; o2[0] = cvt_pk_bf16(e0, e1); o2[1] = cvt_pk_bf16(e2, e3);
          unsigned byte = (unsigned)point*128u + (unsigned)((2*wn+nn)*32 + g*8);
          byte ^= (unsigned)(point&7) << 4;
          *(u32x2*)((char*)h2 + byte) = o2;
        }
      __syncthreads();                                 // C(c)
      #pragma unroll
      for (int t2=0;t2<2;++t2){
        bf16x8 h2f[2];
        #pragma unroll
        for (int pp=0;pp<2;++pp){
          int point = (2*wp+pp)*16 + p;
          unsigned byte = (unsigned)point*128u + (unsigned)t2*64u + (unsigned)g*16u;
          byte ^= (unsigned)(point&7) << 4;
          h2f[pp] = *(const bf16x8*)((const char*)h2 + byte);
        }
        #pragma unroll
        for (int dn=0;dn<2;++dn)
          #pragma unroll
          for (int pp=0;pp<2;++pp)
            acc3[dn][pp] = __builtin_amdgcn_mfma_f32_16x16x32_bf16(
                wf3[(c*2+t2)*2+dn], h2f[pp], acc3[dn][pp], 0, 0, 0);
      }
    }

    // ---- epilogue: +b3, transpose via h2s[0], coalesced 16B stores ----
    #pragma unroll
    for (int dn=0;dn<2;++dn)
      #pragma unroll
      for (int pp=0;pp<2;++pp){
        int point = (2*wp+pp)*16 + p;
        float e0 = acc3[dn][pp][0] + b3p[dn][0];
        float e1 = acc3[dn][pp][1] + b3p[dn][1];
        float e2 = acc3[dn][pp][2] + b3p[dn][2];
        float e3 = acc3[dn][pp][3] + b3p[dn][3];
        u32x2 o2; o2[0] = cvt_pk_bf16(e0, e1); o2[1] = cvt_pk_bf16(e2, e3);
        unsigned byte = (unsigned)point*128u + (unsigned)((2*wn+dn)*32 + g*8);
        byte ^= (unsigned)(point&7) << 4;
        *(u32x2*)((char*)h2s[0] + byte) = o2;
      }
    __syncthreads();                                   // E
    #pragma unroll
    for (int r=0;r<2;++r){
      int pe = w*16 + r*8 + (lane>>3);
      unsigned byte = (unsigned)pe*128u + (unsigned)(lane&7)*16u;
      byte ^= (unsigned)(pe&7) << 4;
      bf16x8 vv = *(const bf16x8*)((const char*)h2s[0] + byte);
      *(bf16x8*)&feat[((size_t)tile*64 + (unsigned)pe)*64u + (unsigned)(lane&7)*8u] = vv;
    }
    __syncthreads();                                   // protect h2s[0]/in_s reuse
  }
}

// gather-max pooling: 4 voxels/block, thread = (voxel, channel)
__global__ __launch_bounds__(256) void k_pool(
    const unsigned* __restrict__ vstart, const unsigned* __restrict__ vcnt,
    const unsigned* __restrict__ perm, const u16* __restrict__ feat,
    float* __restrict__ pooled, int M){
  int vi = blockIdx.x*4 + (threadIdx.x>>6);
  int ch = threadIdx.x & 63;
  if (vi >= M) return;
  unsigned s = vstart[vi], c = vcnt[vi];
  unsigned p0 = perm[s];
  float m = __uint_as_float(((unsigned)feat[(size_t)p0*64u + ch]) << 16);
  for (unsigned i=1; i<c; ++i){
    unsigned p = perm[s+i];
    float v = __uint_as_float(((unsigned)feat[(size_t)p*64u + ch]) << 16);
    m = fmaxf(m, v);
  }
  pooled[(size_t)vi*64u + ch] = m;
}

// fallback (ws too small): round-2 style fused MLP + fkey atomics
__global__ __launch_bounds__(256,4) void k_mlp_atomic(
    const float* __restrict__ pt, const int* __restrict__ xy,
    const float* __restrict__ W1, const float* __restrict__ b1,
    const u16* __restrict__ bp2, const float* __restrict__ b2,
    const u16* __restrict__ bp3, const float* __restrict__ b3,
    const unsigned* __restrict__ rank, unsigned* __restrict__ pooled)
{
  __shared__ __attribute__((aligned(16))) u16 h1s[64*128];
  __shared__ __attribute__((aligned(16))) u16 h2s[2][64*64];
  __shared__ float    in_s[64][3];
  __shared__ unsigned r_s[64];
  const int tid=threadIdx.x, lane=tid&63, w=tid>>6, g=lane>>4, p=lane&15;
  const int wn=w&1, wp=w>>1, p0g=blockIdx.x*64;
  if (tid < 64){
    int pg = p0g + tid;
    int b = pg / NPB;
    int x = xy[2*pg], y = xy[2*pg+1];
    r_s[tid] = rank[(b*GRIDW+x)*GRIDW + y];
    in_s[tid][0]=pt[pg*3+0]; in_s[tid][1]=pt[pg*3+1]; in_s[tid][2]=pt[pg*3+2];
  }
  __syncthreads();
  #pragma unroll
  for (int q=0;q<4;++q){
    int u = q*256 + tid;
    int row = u >> 4, oct = u & 15;
    float x0=in_s[row][0], x1=in_s[row][1], x2=in_s[row][2];
    bf16x8 ov;
    #pragma unroll
    for (int jj=0;jj<8;++jj){
      int j = oct*8 + jj;
      float v = b1[j] + x0*W1[j] + x1*W1[H1D+j] + x2*W1[2*H1D+j];
      ov[jj] = (short)f2bf(fmaxf(v, 0.f));
    }
    unsigned byte = ((unsigned)row<<8) + (unsigned)oct*16u;
    byte ^= (unsigned)(row&7) << 4;
    *(bf16x8*)((char*)h1s + byte) = ov;
  }
  __syncthreads();
  bf16x8 hf[2][4];
  #pragma unroll
  for (int pp=0;pp<2;++pp){
    int row = (2*wp+pp)*16 + p;
    #pragma unroll
    for (int t=0;t<4;++t){
      unsigned byte = ((unsigned)row<<8) + (unsigned)t*64u + (unsigned)g*16u;
      byte ^= (unsigned)(row&7) << 4;
      hf[pp][t] = *(const bf16x8*)((const char*)h1s + byte);
    }
  }
  f32x4 acc3[2][2];
  #pragma unroll
  for (int a=0;a<2;++a)
    #pragma unroll
    for (int b=0;b<2;++b){ acc3[a][b][0]=0.f; acc3[a][b][1]=0.f; acc3[a][b][2]=0.f; acc3[a][b][3]=0.f; }
  for (int c=0;c<4;++c){
    f32x4 acc2[2][2];
    #pragma unroll
    for (int a=0;a<2;++a)
      #pragma unroll
      for (int b=0;b<2;++b){ acc2[a][b][0]=0.f; acc2[a][b][1]=0.f; acc2[a][b][2]=0.f; acc2[a][b][3]=0.f; }
    #pragma unroll
    for (int t=0;t<4;++t){
      bf16x8 wf[2];
      #pragma unroll
      for (int nn=0;nn<2;++nn){
        int ngl = c*4 + 2*wn + nn;
        wf[nn] = *(const bf16x8*)(bp2 + (((ngl*16 + t*4 + g)*16) + p)*8);
      }
      #pragma unroll
      for (int nn=0;nn<2;++nn)
        #pragma unroll
        for (int pp=0;pp<2;++pp)
          acc2[nn][pp] = __builtin_amdgcn_mfma_f32_16x16x32_bf16(wf[nn], hf[pp][t], acc2[nn][pp], 0, 0, 0);
    }
    u16* h2 = h2s[c & 1];
    #pragma unroll
    for (int nn=0;nn<2;++nn){
      int nb = (2*wn+nn)*16 + g*4;
      f32x4 bb = *(const f32x4*)&b2[c*64 + nb];
      #pragma unroll
      for (int pp=0;pp<2;++pp){
        int point = (2*wp+pp)*16 + p;
        s16x4 o;
        #pragma unroll
        for (int i=0;i<4;++i) o[i] = (short)f2bf(fmaxf(acc2[nn][pp][i] + bb[i], 0.f));
        unsigned byte = (unsigned)point*128u + (unsigned)nb*2u;
        byte ^= (unsigned)(point&7) << 4;
        *(s16x4*)((char*)h2 + byte) = o;
      }
    }
    __syncthreads();
    #pragma unroll
    for (int t2=0;t2<2;++t2){
      int s = c*2 + t2;
      bf16x8 w3f[2], h2f[2];
      #pragma unroll
      for (int dn=0;dn<2;++dn){
        int dt = 2*wn + dn;
        w3f[dn] = *(const bf16x8*)(bp3 + (((dt*32 + s*4 + g)*16) + p)*8);
      }
      #pragma unroll
      for (int pp=0;pp<2;++pp){
        int point = (2*wp+pp)*16 + p;
        unsigned byte = (unsigned)point*128u + (unsigned)t2*64u + (unsigned)g*16u;
        byte ^= (unsigned)(point&7) << 4;
        h2f[pp] = *(const bf16x8*)((const char*)h2 + byte);
      }
      #pragma unroll
      for (int dn=0;dn<2;++dn)
        #pragma unroll
        for (int pp=0;pp<2;++pp)
          acc3[dn][pp] = __builtin_amdgcn_mfma_f32_16x16x32_bf16(w3f[dn], h2f[pp], acc3[dn][pp], 0, 0, 0);
    }
  }
  #pragma unroll
  for (int dn=0;dn<2;++dn){
    int db = (2*wn+dn)*16 + g*4;
    f32x4 b3v = *(const f32x4*)&b3[db];
    #pragma unroll
    for (int pp=0;pp<2;++pp){
      int point = (2*wp+pp)*16 + p;
      unsigned base = r_s[point]*64u + (unsigned)db;
      #pragma unroll
      for (int i=0;i<4;++i)
        atomicMax(&pooled[base + i], fkey(acc3[dn][pp][i] + b3v[i]));
    }
  }
}

extern "C" void kernel_launch(void* const* d_in, const int* in_sizes, int n_in,
                              void* d_out, int out_size, void* d_ws, size_t ws_size,
                              hipStream_t stream){
  const float* pt = (const float*)d_in[0];
  const int*   xy = (const int*)d_in[1];
  const float* W1 = (const float*)d_in[2];
  const float* b1 = (const float*)d_in[3];
  const float* W2 = (const float*)d_in[4];
  const float* b2 = (const float*)d_in[5];
  const float* W3 = (const float*)d_in[6];
  const float* b3 = (const float*)d_in[7];
  float* out = (float*)d_out;

  int M = out_size / 67;               // out = unq (M*3) ++ pooled (M*64)

  // workspace layout (u32 units)
  unsigned* counts = (unsigned*)d_ws;
  unsigned* rankF  = counts + NCELL;
  unsigned* rankC  = rankF + NCELL;
  unsigned* bsumF  = rankC + NCELL;
  unsigned* bsumC  = bsumF + 1024;
  unsigned* vstart = bsumC + 1024;
  unsigned* vcnt   = vstart + NPTS;
  unsigned* perm   = vcnt + NPTS;
  u16* bp2 = (u16*)(perm + NPTS);
  u16* bp3 = bp2 + 32768;
  u16* feat = bp3 + 16384;
  size_t need = (size_t)((char*)(feat + (size_t)NPTS*64) - (char*)d_ws);

  hipMemsetAsync(counts, 0, NCELL*sizeof(unsigned), stream);

  if (ws_size >= need){
    // ---- sorted two-phase path (no pooled-atomics) ----
    k_count      <<<(NPTS+255)/256, 256, 0, stream>>>(xy, counts);
    k_pack       <<<192, 256, 0, stream>>>(W2, W3, bp2, bp3);
    k_scan2      <<<SCAN_BLK, 256, 0, stream>>>(counts, rankF, rankC, bsumF, bsumC);
    k_scan_bsum2 <<<1, 1024, 0, stream>>>(bsumF, bsumC);
    k_emit2      <<<NCELL/256, 256, 0, stream>>>(counts, rankF, rankC, bsumF, bsumC,
                                                 out, vstart, vcnt);
    k_scatterp   <<<(NPTS+255)/256, 256, 0, stream>>>(xy, rankC, perm);
    k_mlpp       <<<NBLK, 256, 0, stream>>>(pt, bp2, bp3, W1, b1, b2, b3, feat);
    k_pool       <<<(M+3)/4, 256, 0, stream>>>(vstart, vcnt, perm, feat,
                                               out + 3*(size_t)M, M);
  } else {
    // ---- fallback: fkey atomicMax path ----
    unsigned* pooled = (unsigned*)(out + 3*(size_t)M);
    int n_pooled = M * 64;
    k_count      <<<(NPTS+255)/256, 256, 0, stream>>>(xy, counts);
    k_pack       <<<192, 256, 0, stream>>>(W2, W3, bp2, bp3);
    k_scan2      <<<SCAN_BLK, 256, 0, stream>>>(counts, rankF, rankC, bsumF, bsumC);
    k_scan_bsum2 <<<1, 1024, 0, stream>>>(bsumF, bsumC);
    k_emit2      <<<NCELL/256, 256, 0, stream>>>(counts, rankF, rankC, bsumF, bsumC,
                                                 out, nullptr, nullptr);
    k_init_pooled<<<2048, 256, 0, stream>>>(pooled, n_pooled);
    k_mlp_atomic <<<NPTS/64, 256, 0, stream>>>(pt, xy, W1, b1, bp2, b2, bp3, b3,
                                               rankF, pooled);
    k_decode     <<<2048, 256, 0, stream>>>(pooled, n_pooled);
  }
}